// Round 1
// baseline (687.682 us; speedup 1.0000x reference)
//
#include <hip/hip_runtime.h>
#include <hip/hip_bf16.h>

// PGExplainer fused edge-MLP.
// inputs (d_in order): embeds[N,128] f32, W1[384,64] f32, b1[64] f32,
//   W2[64,1] f32, b2[1] f32, u[E,1] f32, src[E] i32, dst[E] i32, n[1] i32
// out: mask[E] f32
//
// Strategy (round 1, fp32 baseline):
//  - prep kernel: transpose W1 rows 0..255 -> W1T[64][256] in ws, and fold the
//    constant node-embedding contribution + b1 into cnode[64].
//  - main kernel: one thread per edge; 4 blocks of 16 hidden units with
//    statically-indexed acc[16]; inputs loaded as float4; weights read from
//    wave-uniform addresses (scalar-load friendly).

#define D 128
#define HID 64
#define KTOT 256   // src(128) + dst(128); node part folded into cnode

__global__ __launch_bounds__(256) void pg_prep(
    const float* __restrict__ embeds, const float* __restrict__ W1,
    const float* __restrict__ b1, const int* __restrict__ nidx,
    float* __restrict__ w1t, float* __restrict__ cnode)
{
    int t = threadIdx.x;
    // transpose W1[0:256][64] -> w1t[64][256]
    for (int idx = t; idx < HID * KTOT; idx += 256) {
        int j = idx >> 8;        // 0..63
        int k = idx & 255;       // 0..255
        w1t[idx] = W1[k * HID + j];
    }
    // cnode[j] = b1[j] + sum_k embeds[n][k] * W1[256+k][j]
    if (t < HID) {
        int n = nidx[0];
        const float* nr = embeds + (long)n * D;
        float c = b1[t];
        for (int k = 0; k < D; ++k)
            c = fmaf(nr[k], W1[(KTOT + k) * HID + t], c);
        cnode[t] = c;
    }
}

__global__ __launch_bounds__(256) void pg_edge(
    const float* __restrict__ embeds,
    const float* __restrict__ w1t, const float* __restrict__ cnode,
    const float* __restrict__ W2, const float* __restrict__ b2,
    const float* __restrict__ u,
    const int* __restrict__ src, const int* __restrict__ dst,
    float* __restrict__ out, int E)
{
    int e = blockIdx.x * 256 + threadIdx.x;
    if (e >= E) return;

    const float* srow = embeds + (long)src[e] * D;
    const float* drow = embeds + (long)dst[e] * D;

    float sw = b2[0];

    #pragma unroll 1
    for (int jb = 0; jb < 4; ++jb) {
        float acc[16];
        #pragma unroll
        for (int jj = 0; jj < 16; ++jj) acc[jj] = cnode[jb * 16 + jj];

        const float* w1b = w1t + jb * 16 * KTOT;

        #pragma unroll 1
        for (int c = 0; c < 16; ++c) {
            const float* rowp = (c < 8) ? srow : drow;
            int kb = (c * 16) & (D - 1);
            float4 v0 = *reinterpret_cast<const float4*>(rowp + kb);
            float4 v1 = *reinterpret_cast<const float4*>(rowp + kb + 4);
            float4 v2 = *reinterpret_cast<const float4*>(rowp + kb + 8);
            float4 v3 = *reinterpret_cast<const float4*>(rowp + kb + 12);
            float in[16];
            *reinterpret_cast<float4*>(&in[0])  = v0;
            *reinterpret_cast<float4*>(&in[4])  = v1;
            *reinterpret_cast<float4*>(&in[8])  = v2;
            *reinterpret_cast<float4*>(&in[12]) = v3;

            const float* wbase = w1b + c * 16;
            #pragma unroll
            for (int jj = 0; jj < 16; ++jj) {
                const float* w = wbase + jj * KTOT;
                #pragma unroll
                for (int kk = 0; kk < 16; ++kk)
                    acc[jj] = fmaf(in[kk], w[kk], acc[jj]);
            }
        }

        #pragma unroll
        for (int jj = 0; jj < 16; ++jj) {
            float h = acc[jj] > 0.f ? acc[jj] : 0.f;
            sw = fmaf(h, W2[jb * 16 + jj], sw);
        }
    }

    // Gumbel-sigmoid gate (training=true), bias = 0.0001, TEMP = 5
    float uu  = u[e];
    float eps = 0.9999f - 0.9998f * uu;          // (bias-(1-bias))*u + (1-bias)
    float gate = logf(eps) - log1pf(-eps);
    float x = (gate + sw) * 0.2f;                // / TEMP
    out[e] = 1.f / (1.f + expf(-x));
}

extern "C" void kernel_launch(void* const* d_in, const int* in_sizes, int n_in,
                              void* d_out, int out_size, void* d_ws, size_t ws_size,
                              hipStream_t stream) {
    const float* embeds = (const float*)d_in[0];
    const float* W1     = (const float*)d_in[1];
    const float* b1     = (const float*)d_in[2];
    const float* W2     = (const float*)d_in[3];
    const float* b2     = (const float*)d_in[4];
    const float* u      = (const float*)d_in[5];
    const int*   src    = (const int*)d_in[6];
    const int*   dst    = (const int*)d_in[7];
    const int*   nidx   = (const int*)d_in[8];

    int E = in_sizes[6];

    float* w1t   = (float*)d_ws;                  // 64*256 f32 = 64 KiB
    float* cnode = w1t + HID * KTOT;              // 64 f32

    pg_prep<<<1, 256, 0, stream>>>(embeds, W1, b1, nidx, w1t, cnode);

    int grid = (E + 255) / 256;
    pg_edge<<<grid, 256, 0, stream>>>(embeds, w1t, cnode, W2, b2, u, src, dst,
                                      (float*)d_out, E);
}

// Round 3
// 330.895 us; speedup vs baseline: 2.0782x; 2.0782x over previous
//
#include <hip/hip_runtime.h>
#include <hip/hip_bf16.h>

// PGExplainer fused edge-MLP — round 3: per-node precompute (compile fix).
//
// inputs (d_in order): embeds[N,128] f32, W1[384,64] f32, b1[64] f32,
//   W2[64,1] f32, b2[1] f32, u[E,1] f32, src[E] i32, dst[E] i32, n[1] i32
// out: mask[E] f32
//
// Math: h = relu(embeds[src]@W1a + embeds[dst]@W1b + (embeds[n]@W1c + b1))
//       sw = h@W2 + b2;  mask = sigmoid((gumbel(u) + sw)/TEMP)
// Precompute P1 = embeds@W1a, P2 = embeds@W1b (bf16, [N,64]) once per launch;
// per edge only two 128B row gathers + 64 fma remain.

#define D 128
#define HID 64

typedef __attribute__((ext_vector_type(8))) unsigned short ushort8_t;

__device__ inline float bf2f(unsigned short v) {
    union { unsigned int u; float f; } x;
    x.u = ((unsigned int)v) << 16;
    return x.f;
}

__device__ inline unsigned short f2bf(float f) {
    union { float f; unsigned int u; } x;
    x.f = f;
    unsigned int r = x.u + 0x7FFFu + ((x.u >> 16) & 1u);   // RNE
    return (unsigned short)(r >> 16);
}

// --- prep: transpose W1a/W1b -> [64][128], fold node term + b1 into cnode ---
__global__ __launch_bounds__(256) void pg_prep(
    const float* __restrict__ embeds, const float* __restrict__ W1,
    const float* __restrict__ b1, const int* __restrict__ nidx,
    float* __restrict__ w1tA, float* __restrict__ w1tB,
    float* __restrict__ cnode)
{
    int t = threadIdx.x;
    for (int idx = t; idx < HID * D; idx += 256) {
        int j = idx >> 7;        // 0..63
        int k = idx & 127;       // 0..127
        w1tA[idx] = W1[k * HID + j];
        w1tB[idx] = W1[(D + k) * HID + j];
    }
    if (t < HID) {
        int n = nidx[0];
        const float* nr = embeds + (size_t)n * D;
        float c = b1[t];
        for (int k = 0; k < D; ++k)
            c = fmaf(nr[k], W1[(2 * D + k) * HID + t], c);
        cnode[t] = c;
    }
}

// --- per-node projections: P1 = embeds@W1a, P2 = embeds@W1b (bf16) ---
__global__ __launch_bounds__(256) void pg_nodes(
    const float* __restrict__ embeds,
    const float* __restrict__ w1tA, const float* __restrict__ w1tB,
    unsigned short* __restrict__ P1, unsigned short* __restrict__ P2, int N)
{
    int node = blockIdx.x * 256 + threadIdx.x;
    if (node >= N) return;
    const float* row = embeds + (size_t)node * D;

    #pragma unroll 1
    for (int jb = 0; jb < 4; ++jb) {
        float acc1[16], acc2[16];
        #pragma unroll
        for (int jj = 0; jj < 16; ++jj) { acc1[jj] = 0.f; acc2[jj] = 0.f; }

        #pragma unroll 1
        for (int c = 0; c < 8; ++c) {
            float in[16];
            *reinterpret_cast<float4*>(&in[0])  = *reinterpret_cast<const float4*>(row + c * 16);
            *reinterpret_cast<float4*>(&in[4])  = *reinterpret_cast<const float4*>(row + c * 16 + 4);
            *reinterpret_cast<float4*>(&in[8])  = *reinterpret_cast<const float4*>(row + c * 16 + 8);
            *reinterpret_cast<float4*>(&in[12]) = *reinterpret_cast<const float4*>(row + c * 16 + 12);

            #pragma unroll
            for (int jj = 0; jj < 16; ++jj) {
                const float* wa = w1tA + (jb * 16 + jj) * D + c * 16;
                const float* wb = w1tB + (jb * 16 + jj) * D + c * 16;
                #pragma unroll
                for (int kk = 0; kk < 16; ++kk) {
                    acc1[jj] = fmaf(in[kk], wa[kk], acc1[jj]);
                    acc2[jj] = fmaf(in[kk], wb[kk], acc2[jj]);
                }
            }
        }

        unsigned short* o1 = P1 + (size_t)node * HID + jb * 16;
        unsigned short* o2 = P2 + (size_t)node * HID + jb * 16;
        #pragma unroll
        for (int jj = 0; jj < 16; ++jj) {
            o1[jj] = f2bf(acc1[jj]);
            o2[jj] = f2bf(acc2[jj]);
        }
    }
}

// --- per-edge: gather P1[src], P2[dst]; relu-dot with W2; gumbel-sigmoid ---
__global__ __launch_bounds__(256) void pg_edge2(
    const unsigned short* __restrict__ P1, const unsigned short* __restrict__ P2,
    const float* __restrict__ cnode, const float* __restrict__ W2,
    const float* __restrict__ b2, const float* __restrict__ u,
    const int* __restrict__ src, const int* __restrict__ dst,
    float* __restrict__ out, int E)
{
    int e = blockIdx.x * 256 + threadIdx.x;
    if (e >= E) return;

    const ushort8_t* r1 = reinterpret_cast<const ushort8_t*>(P1 + (size_t)src[e] * HID);
    const ushort8_t* r2 = reinterpret_cast<const ushort8_t*>(P2 + (size_t)dst[e] * HID);

    // issue all 16 row loads up front (16B each) for max MLP
    ushort8_t a[8], b[8];
    #pragma unroll
    for (int jb = 0; jb < 8; ++jb) { a[jb] = r1[jb]; b[jb] = r2[jb]; }

    float sw = b2[0];
    #pragma unroll
    for (int jb = 0; jb < 8; ++jb) {
        #pragma unroll
        for (int jj = 0; jj < 8; ++jj) {
            float h = bf2f(a[jb][jj]) + bf2f(b[jb][jj]) + cnode[jb * 8 + jj];
            h = h > 0.f ? h : 0.f;
            sw = fmaf(h, W2[jb * 8 + jj], sw);
        }
    }

    float uu  = u[e];
    float eps = 0.9999f - 0.9998f * uu;          // (bias-(1-bias))*u + (1-bias)
    float gate = logf(eps) - log1pf(-eps);
    float x = (gate + sw) * 0.2f;                // / TEMP
    out[e] = 1.f / (1.f + expf(-x));
}

extern "C" void kernel_launch(void* const* d_in, const int* in_sizes, int n_in,
                              void* d_out, int out_size, void* d_ws, size_t ws_size,
                              hipStream_t stream) {
    const float* embeds = (const float*)d_in[0];
    const float* W1     = (const float*)d_in[1];
    const float* b1     = (const float*)d_in[2];
    const float* W2     = (const float*)d_in[3];
    const float* b2     = (const float*)d_in[4];
    const float* u      = (const float*)d_in[5];
    const int*   src    = (const int*)d_in[6];
    const int*   dst    = (const int*)d_in[7];
    const int*   nidx   = (const int*)d_in[8];

    int E = in_sizes[6];
    int N = in_sizes[0] / D;

    // ws layout: w1tA 32KB | w1tB 32KB | cnode 256B(+pad) | P1 6.4MB | P2 6.4MB
    float* w1tA  = (float*)d_ws;
    float* w1tB  = w1tA + HID * D;
    float* cnode = w1tB + HID * D;
    unsigned short* P1 = (unsigned short*)(cnode + 64);
    unsigned short* P2 = P1 + (size_t)N * HID;

    pg_prep<<<1, 256, 0, stream>>>(embeds, W1, b1, nidx, w1tA, w1tB, cnode);
    pg_nodes<<<(N + 255) / 256, 256, 0, stream>>>(embeds, w1tA, w1tB, P1, P2, N);
    pg_edge2<<<(E + 255) / 256, 256, 0, stream>>>(P1, P2, cnode, W2, b2, u,
                                                  src, dst, (float*)d_out, E);
}

// Round 4
// 150.210 us; speedup vs baseline: 4.5781x; 2.2029x over previous
//
#include <hip/hip_runtime.h>
#include <hip/hip_bf16.h>

// PGExplainer fused edge-MLP — round 4: parallelized node projections.
//
// inputs (d_in order): embeds[N,128] f32, W1[384,64] f32, b1[64] f32,
//   W2[64,1] f32, b2[1] f32, u[E,1] f32, src[E] i32, dst[E] i32, n[1] i32
// out: mask[E] f32
//
// Math: h = relu(embeds[src]@W1a + embeds[dst]@W1b + (embeds[n]@W1c + b1))
//       sw = h@W2 + b2;  mask = sigmoid((gumbel(u) + sw)/TEMP)
// P1 = embeds@W1a, P2 = embeds@W1b precomputed in bf16 [N,64].
// pg_nodes: 16 threads/node, 4 hidden units/thread, W1 read in original
// [k][j] layout -> float4 weight loads are fully coalesced (no transpose).

#define D 128
#define HID 64

typedef __attribute__((ext_vector_type(8))) unsigned short ushort8_t;
typedef __attribute__((ext_vector_type(4))) unsigned short ushort4_t;

__device__ inline float bf2f(unsigned short v) {
    union { unsigned int u; float f; } x;
    x.u = ((unsigned int)v) << 16;
    return x.f;
}

__device__ inline unsigned short f2bf(float f) {
    union { float f; unsigned int u; } x;
    x.f = f;
    unsigned int r = x.u + 0x7FFFu + ((x.u >> 16) & 1u);   // RNE
    return (unsigned short)(r >> 16);
}

// --- prep: fold node term + b1 into cnode[64] ---
__global__ __launch_bounds__(64) void pg_prep(
    const float* __restrict__ embeds, const float* __restrict__ W1,
    const float* __restrict__ b1, const int* __restrict__ nidx,
    float* __restrict__ cnode)
{
    int t = threadIdx.x;   // 0..63
    int n = nidx[0];
    const float* nr = embeds + (size_t)n * D;
    float c = b1[t];
    #pragma unroll 4
    for (int k = 0; k < D; ++k)
        c = fmaf(nr[k], W1[(2 * D + k) * HID + t], c);
    cnode[t] = c;
}

// --- per-node projections: P1 = embeds@W1a, P2 = embeds@W1b (bf16) ---
// 16 threads per node; thread (node, g) computes j = 4g..4g+3.
__global__ __launch_bounds__(256) void pg_nodes(
    const float* __restrict__ embeds, const float* __restrict__ W1,
    unsigned short* __restrict__ P1, unsigned short* __restrict__ P2, int N)
{
    int t = blockIdx.x * 256 + threadIdx.x;
    int node = t >> 4;
    if (node >= N) return;
    int j0 = (t & 15) * 4;

    const float* row = embeds + (size_t)node * D;
    const float* Wa = W1 + j0;               // W1a[k][j] = W1[k*HID + j]
    const float* Wb = W1 + (size_t)D * HID + j0;

    float acc1[4] = {0.f, 0.f, 0.f, 0.f};
    float acc2[4] = {0.f, 0.f, 0.f, 0.f};

    #pragma unroll 2
    for (int kb = 0; kb < D / 4; ++kb) {
        float4 rv = *reinterpret_cast<const float4*>(row + kb * 4);
        float r[4] = {rv.x, rv.y, rv.z, rv.w};
        #pragma unroll
        for (int kk = 0; kk < 4; ++kk) {
            int k = kb * 4 + kk;
            float4 wa = *reinterpret_cast<const float4*>(Wa + (size_t)k * HID);
            float4 wb = *reinterpret_cast<const float4*>(Wb + (size_t)k * HID);
            acc1[0] = fmaf(r[kk], wa.x, acc1[0]);
            acc1[1] = fmaf(r[kk], wa.y, acc1[1]);
            acc1[2] = fmaf(r[kk], wa.z, acc1[2]);
            acc1[3] = fmaf(r[kk], wa.w, acc1[3]);
            acc2[0] = fmaf(r[kk], wb.x, acc2[0]);
            acc2[1] = fmaf(r[kk], wb.y, acc2[1]);
            acc2[2] = fmaf(r[kk], wb.z, acc2[2]);
            acc2[3] = fmaf(r[kk], wb.w, acc2[3]);
        }
    }

    ushort4_t o1, o2;
    #pragma unroll
    for (int jj = 0; jj < 4; ++jj) { o1[jj] = f2bf(acc1[jj]); o2[jj] = f2bf(acc2[jj]); }
    *reinterpret_cast<ushort4_t*>(P1 + (size_t)node * HID + j0) = o1;
    *reinterpret_cast<ushort4_t*>(P2 + (size_t)node * HID + j0) = o2;
}

// --- per-edge: gather P1[src], P2[dst]; relu-dot with W2; gumbel-sigmoid ---
__global__ __launch_bounds__(256) void pg_edge2(
    const unsigned short* __restrict__ P1, const unsigned short* __restrict__ P2,
    const float* __restrict__ cnode, const float* __restrict__ W2,
    const float* __restrict__ b2, const float* __restrict__ u,
    const int* __restrict__ src, const int* __restrict__ dst,
    float* __restrict__ out, int E)
{
    int e = blockIdx.x * 256 + threadIdx.x;
    if (e >= E) return;

    const ushort8_t* r1 = reinterpret_cast<const ushort8_t*>(P1 + (size_t)src[e] * HID);
    const ushort8_t* r2 = reinterpret_cast<const ushort8_t*>(P2 + (size_t)dst[e] * HID);

    ushort8_t a[8], b[8];
    #pragma unroll
    for (int jb = 0; jb < 8; ++jb) { a[jb] = r1[jb]; b[jb] = r2[jb]; }

    float sw = b2[0];
    #pragma unroll
    for (int jb = 0; jb < 8; ++jb) {
        #pragma unroll
        for (int jj = 0; jj < 8; ++jj) {
            float h = bf2f(a[jb][jj]) + bf2f(b[jb][jj]) + cnode[jb * 8 + jj];
            h = h > 0.f ? h : 0.f;
            sw = fmaf(h, W2[jb * 8 + jj], sw);
        }
    }

    float uu  = u[e];
    float eps = 0.9999f - 0.9998f * uu;          // (bias-(1-bias))*u + (1-bias)
    float gate = logf(eps) - log1pf(-eps);
    float x = (gate + sw) * 0.2f;                // / TEMP
    out[e] = 1.f / (1.f + expf(-x));
}

extern "C" void kernel_launch(void* const* d_in, const int* in_sizes, int n_in,
                              void* d_out, int out_size, void* d_ws, size_t ws_size,
                              hipStream_t stream) {
    const float* embeds = (const float*)d_in[0];
    const float* W1     = (const float*)d_in[1];
    const float* b1     = (const float*)d_in[2];
    const float* W2     = (const float*)d_in[3];
    const float* b2     = (const float*)d_in[4];
    const float* u      = (const float*)d_in[5];
    const int*   src    = (const int*)d_in[6];
    const int*   dst    = (const int*)d_in[7];
    const int*   nidx   = (const int*)d_in[8];

    int E = in_sizes[6];
    int N = in_sizes[0] / D;

    // ws layout: cnode 64 f32 | P1 [N*64] bf16 | P2 [N*64] bf16
    float* cnode = (float*)d_ws;
    unsigned short* P1 = (unsigned short*)(cnode + 64);
    unsigned short* P2 = P1 + (size_t)N * HID;

    pg_prep<<<1, 64, 0, stream>>>(embeds, W1, b1, nidx, cnode);
    pg_nodes<<<(N * 16 + 255) / 256, 256, 0, stream>>>(embeds, W1, P1, P2, N);
    pg_edge2<<<(E + 255) / 256, 256, 0, stream>>>(P1, P2, cnode, W2, b2, u,
                                                  src, dst, (float*)d_out, E);
}

// Round 5
// 93.155 us; speedup vs baseline: 7.3821x; 1.6125x over previous
//
#include <hip/hip_runtime.h>
#include <hip/hip_bf16.h>

// PGExplainer fused edge-MLP — round 5: LDS-staged weights for node GEMM.
//
// inputs (d_in order): embeds[N,128] f32, W1[384,64] f32, b1[64] f32,
//   W2[64,1] f32, b2[1] f32, u[E,1] f32, src[E] i32, dst[E] i32, n[1] i32
// out: mask[E] f32
//
// Math: h = relu(embeds[src]@W1a + embeds[dst]@W1b + (embeds[n]@W1c + b1))
//       sw = h@W2 + b2;  mask = sigmoid((gumbel(u) + sw)/TEMP)
// P[node][128] bf16 = [embeds@W1a | embeds@W1b] precomputed once; per edge
// only two 128B row gathers + 64 fma remain.
//
// pg_nodes: weights transposed to w[k][128] and staged in LDS (64KB);
// thread = (4 nodes, 4 cols): 2048 FMA vs ~256 load instrs -> VALU-bound.

#define D 128
#define HID 64

typedef __attribute__((ext_vector_type(8))) unsigned short ushort8_t;
typedef __attribute__((ext_vector_type(4))) unsigned short ushort4_t;

__device__ inline float bf2f(unsigned short v) {
    union { unsigned int u; float f; } x;
    x.u = ((unsigned int)v) << 16;
    return x.f;
}

__device__ inline unsigned short f2bf(float f) {
    union { float f; unsigned int u; } x;
    x.f = f;
    unsigned int r = x.u + 0x7FFFu + ((x.u >> 16) & 1u);   // RNE
    return (unsigned short)(r >> 16);
}

// --- prep: w1t[k][j] combined transpose + fold node term + b1 into cnode ---
__global__ __launch_bounds__(256) void pg_prep(
    const float* __restrict__ embeds, const float* __restrict__ W1,
    const float* __restrict__ b1, const int* __restrict__ nidx,
    float* __restrict__ w1t, float* __restrict__ cnode)
{
    int t = threadIdx.x;
    for (int idx = t; idx < D * 2 * HID; idx += 256) {
        int k = idx >> 7;          // 0..127
        int j = idx & 127;         // 0..127
        w1t[idx] = (j < HID) ? W1[k * HID + j]
                             : W1[(D + k) * HID + (j - HID)];
    }
    if (t < HID) {
        int n = nidx[0];
        const float* nr = embeds + (size_t)n * D;
        float c = b1[t];
        #pragma unroll 4
        for (int k = 0; k < D; ++k)
            c = fmaf(nr[k], W1[(2 * D + k) * HID + t], c);
        cnode[t] = c;
    }
}

// --- node projections: P[node][0:64]=embeds@W1a, [64:128]=embeds@W1b ---
__global__ __launch_bounds__(256, 2) void pg_nodes(
    const float* __restrict__ embeds, const float* __restrict__ w1t,
    unsigned short* __restrict__ P, int N)
{
    __shared__ float wl[D * 2 * HID];          // wl[k][j], 64 KiB
    {
        const float4* s4 = reinterpret_cast<const float4*>(w1t);
        float4* d4 = reinterpret_cast<float4*>(wl);
        #pragma unroll
        for (int i = 0; i < 16; ++i)           // 16*256 float4 = 64KB
            d4[threadIdx.x + i * 256] = s4[threadIdx.x + i * 256];
    }
    __syncthreads();

    int g  = threadIdx.x >> 5;                 // 0..7 node group
    int j0 = (threadIdx.x & 31) * 4;           // 0..124
    int n0 = blockIdx.x * 32 + g * 4;

    int ni[4];
    #pragma unroll
    for (int i = 0; i < 4; ++i) ni[i] = (n0 + i < N) ? (n0 + i) : (N - 1);

    float acc[4][4] = {{0.f}};

    #pragma unroll 1
    for (int kc = 0; kc < 32; ++kc) {          // k chunks of 4
        float a[4][4];
        #pragma unroll
        for (int i = 0; i < 4; ++i) {
            float4 v = *reinterpret_cast<const float4*>(
                embeds + (size_t)ni[i] * D + kc * 4);
            a[i][0] = v.x; a[i][1] = v.y; a[i][2] = v.z; a[i][3] = v.w;
        }
        #pragma unroll
        for (int kk = 0; kk < 4; ++kk) {
            float4 w = *reinterpret_cast<const float4*>(
                &wl[(kc * 4 + kk) * 128 + j0]);
            #pragma unroll
            for (int i = 0; i < 4; ++i) {
                acc[i][0] = fmaf(a[i][kk], w.x, acc[i][0]);
                acc[i][1] = fmaf(a[i][kk], w.y, acc[i][1]);
                acc[i][2] = fmaf(a[i][kk], w.z, acc[i][2]);
                acc[i][3] = fmaf(a[i][kk], w.w, acc[i][3]);
            }
        }
    }

    #pragma unroll
    for (int i = 0; i < 4; ++i) {
        if (n0 + i < N) {
            ushort4_t o;
            o[0] = f2bf(acc[i][0]); o[1] = f2bf(acc[i][1]);
            o[2] = f2bf(acc[i][2]); o[3] = f2bf(acc[i][3]);
            *reinterpret_cast<ushort4_t*>(P + (size_t)(n0 + i) * 128 + j0) = o;
        }
    }
}

// --- per-edge: gather P[src][0:64], P[dst][64:128]; relu-dot W2; gumbel ---
__global__ __launch_bounds__(256) void pg_edge2(
    const unsigned short* __restrict__ P,
    const float* __restrict__ cnode, const float* __restrict__ W2,
    const float* __restrict__ b2, const float* __restrict__ u,
    const int* __restrict__ src, const int* __restrict__ dst,
    float* __restrict__ out, int E)
{
    int e = blockIdx.x * 256 + threadIdx.x;
    if (e >= E) return;

    const ushort8_t* r1 = reinterpret_cast<const ushort8_t*>(P + (size_t)src[e] * 128);
    const ushort8_t* r2 = reinterpret_cast<const ushort8_t*>(P + (size_t)dst[e] * 128 + HID);

    ushort8_t a[8], b[8];
    #pragma unroll
    for (int jb = 0; jb < 8; ++jb) { a[jb] = r1[jb]; b[jb] = r2[jb]; }

    float sw = b2[0];
    #pragma unroll
    for (int jb = 0; jb < 8; ++jb) {
        #pragma unroll
        for (int jj = 0; jj < 8; ++jj) {
            float h = bf2f(a[jb][jj]) + bf2f(b[jb][jj]) + cnode[jb * 8 + jj];
            h = h > 0.f ? h : 0.f;
            sw = fmaf(h, W2[jb * 8 + jj], sw);
        }
    }

    float uu  = u[e];
    float eps = 0.9999f - 0.9998f * uu;          // (bias-(1-bias))*u + (1-bias)
    float gate = logf(eps) - log1pf(-eps);
    float x = (gate + sw) * 0.2f;                // / TEMP
    out[e] = 1.f / (1.f + expf(-x));
}

extern "C" void kernel_launch(void* const* d_in, const int* in_sizes, int n_in,
                              void* d_out, int out_size, void* d_ws, size_t ws_size,
                              hipStream_t stream) {
    const float* embeds = (const float*)d_in[0];
    const float* W1     = (const float*)d_in[1];
    const float* b1     = (const float*)d_in[2];
    const float* W2     = (const float*)d_in[3];
    const float* b2     = (const float*)d_in[4];
    const float* u      = (const float*)d_in[5];
    const int*   src    = (const int*)d_in[6];
    const int*   dst    = (const int*)d_in[7];
    const int*   nidx   = (const int*)d_in[8];

    int E = in_sizes[6];
    int N = in_sizes[0] / D;

    // ws: w1t[128][128] f32 64KB | cnode 64 f32 | P [N][128] bf16 12.8MB
    float* w1t   = (float*)d_ws;
    float* cnode = w1t + D * 2 * HID;
    unsigned short* P = (unsigned short*)(cnode + 64);

    pg_prep<<<1, 256, 0, stream>>>(embeds, W1, b1, nidx, w1t, cnode);
    pg_nodes<<<(N + 31) / 32, 256, 0, stream>>>(embeds, w1t, P, N);
    pg_edge2<<<(E + 255) / 256, 256, 0, stream>>>(P, cnode, W2, b2, u,
                                                  src, dst, (float*)d_out, E);
}

// Round 6
// 55.615 us; speedup vs baseline: 12.3651x; 1.6750x over previous
//
#include <hip/hip_runtime.h>
#include <hip/hip_bf16.h>

// PGExplainer fused edge-MLP — round 6: MFMA node GEMM + fp8(e5m2) P table.
//
// inputs (d_in order): embeds[N,128] f32, W1[384,64] f32, b1[64] f32,
//   W2[64,1] f32, b2[1] f32, u[E,1] f32, src[E] i32, dst[E] i32, n[1] i32
// out: mask[E] f32
//
// h = relu(embeds[src]@W1a + embeds[dst]@W1b + (embeds[n]@W1c + b1))
// sw = h@W2 + b2;  mask = sigmoid((gumbel(u) + sw)/TEMP)
//
// P[node][128] (1B e5m2 each): cols 0..63 = embeds@W1a, 64..127 = embeds@W1b.
// pg_nodes: mfma_f32_16x16x32_bf16; B-operand pre-ordered in per-lane
// fragment layout by pg_prep -> conflict-free ds_read_b128.
// pg_edge: two 64B gathers + in-register e5m2 decode + relu-dot + gumbel.

#define D 128
#define HID 64

typedef __attribute__((ext_vector_type(8))) short short8;
typedef __attribute__((ext_vector_type(4))) float f32x4;

__device__ inline unsigned short f2bf(float f) {
    union { float f; unsigned int u; } x;
    x.f = f;
    unsigned int r = x.u + 0x7FFFu + ((x.u >> 16) & 1u);   // RNE
    return (unsigned short)(r >> 16);
}

// e5m2 = top byte of IEEE f16 (we control both encode and decode).
__device__ inline unsigned char f2e5(float f) {
    _Float16 h = (_Float16)f;
    unsigned short u;
    __builtin_memcpy(&u, &h, 2);
    unsigned short r = (unsigned short)(u + 0x7Fu + ((u >> 8) & 1u));  // RNE to 8b
    return (unsigned char)(r >> 8);
}
__device__ inline float e5(unsigned short hibits) {   // hibits = byte<<8
    _Float16 h;
    __builtin_memcpy(&h, &hibits, 2);
    return (float)h;
}

// --- prep: build fragment-ordered B table (bf16) + cnode[64] ---
// bfrag[((ks*8+ct)*64+lane)*8+j] = Wcomb[k=ks*32+(lane>>4)*8+j][col=ct*16+(lane&15)]
// Wcomb[k][col] = col<64 ? W1[k][col] : W1[128+k][col-64]
__global__ __launch_bounds__(256) void pg_prep(
    const float* __restrict__ embeds, const float* __restrict__ W1,
    const float* __restrict__ b1, const int* __restrict__ nidx,
    unsigned short* __restrict__ bfrag, float* __restrict__ cnode)
{
    int t = threadIdx.x;
    for (int i = t; i < 16384; i += 256) {
        int j    = i & 7;
        int lane = (i >> 3) & 63;
        int ct   = (i >> 9) & 7;
        int ks   = i >> 12;
        int k    = ks * 32 + (lane >> 4) * 8 + j;
        int col  = ct * 16 + (lane & 15);
        float w  = (col < HID) ? W1[k * HID + col]
                               : W1[(D + k) * HID + (col - HID)];
        bfrag[i] = f2bf(w);
    }
    if (t < HID) {
        int n = nidx[0];
        const float* nr = embeds + (size_t)n * D;
        float c = b1[t];
        #pragma unroll 4
        for (int k = 0; k < D; ++k)
            c = fmaf(nr[k], W1[(2 * D + k) * HID + t], c);
        cnode[t] = c;
    }
}

// --- node projections via MFMA: P[node][128] e5m2 ---
__global__ __launch_bounds__(256) void pg_nodes(
    const float* __restrict__ embeds, const unsigned short* __restrict__ bfrag,
    unsigned char* __restrict__ P, int N, int NTILES)
{
    __shared__ short wl[16384];                       // 32 KiB B-frag table
    {
        const uint4* s = reinterpret_cast<const uint4*>(bfrag);
        uint4* d = reinterpret_cast<uint4*>(wl);
        #pragma unroll
        for (int i = 0; i < 8; ++i)                   // 2048 uint4 total
            d[threadIdx.x + i * 256] = s[threadIdx.x + i * 256];
    }
    __syncthreads();

    int wave  = threadIdx.x >> 6;
    int lane  = threadIdx.x & 63;
    int ntile = blockIdx.x * 4 + wave;
    if (ntile >= NTILES) return;

    int kg = lane >> 4;                               // 0..3 k-group
    int nr = ntile * 16 + (lane & 15);                // A row (node)
    if (nr >= N) nr = N - 1;
    const float* row = embeds + (size_t)nr * D + kg * 8;

    // A fragments: af[ks][j] = bf16(embeds[nr][ks*32 + kg*8 + j])
    short8 af[4];
    #pragma unroll
    for (int ks = 0; ks < 4; ++ks) {
        float4 v0 = *reinterpret_cast<const float4*>(row + ks * 32);
        float4 v1 = *reinterpret_cast<const float4*>(row + ks * 32 + 4);
        union { float f; unsigned u; } c[8];
        c[0].f = v0.x; c[1].f = v0.y; c[2].f = v0.z; c[3].f = v0.w;
        c[4].f = v1.x; c[5].f = v1.y; c[6].f = v1.z; c[7].f = v1.w;
        union { unsigned u[4]; short8 s; } pk;
        #pragma unroll
        for (int p = 0; p < 4; ++p)                   // truncate-pack 2 f32 -> u32
            pk.u[p] = (c[2 * p + 1].u & 0xFFFF0000u) | (c[2 * p].u >> 16);
        af[ks] = pk.s;
    }

    const short8* wl8 = reinterpret_cast<const short8*>(wl);

    f32x4 acc[8];
    #pragma unroll
    for (int ct = 0; ct < 8; ++ct) acc[ct] = (f32x4){0.f, 0.f, 0.f, 0.f};

    #pragma unroll
    for (int ct = 0; ct < 8; ++ct) {
        #pragma unroll
        for (int ks = 0; ks < 4; ++ks) {
            short8 bf = wl8[(ks * 8 + ct) * 64 + lane];
            acc[ct] = __builtin_amdgcn_mfma_f32_16x16x32_bf16(af[ks], bf, acc[ct], 0, 0, 0);
        }
    }

    // C layout: col = ct*16 + (lane&15), row(node) = ntile*16 + (lane>>4)*4 + reg
    int node0 = ntile * 16 + kg * 4;
    #pragma unroll
    for (int ct = 0; ct < 8; ++ct) {
        int col = ct * 16 + (lane & 15);
        #pragma unroll
        for (int r = 0; r < 4; ++r) {
            int node = node0 + r;
            if (node < N)
                P[(size_t)node * 128 + col] = f2e5(acc[ct][r]);
        }
    }
}

// --- per-edge: gather 64B src + 64B dst, decode e5m2, relu-dot, gumbel ---
__global__ __launch_bounds__(256) void pg_edge(
    const unsigned char* __restrict__ P,
    const float* __restrict__ cnode, const float* __restrict__ W2,
    const float* __restrict__ b2, const float* __restrict__ u,
    const int* __restrict__ src, const int* __restrict__ dst,
    float* __restrict__ out, int E)
{
    int e = blockIdx.x * 256 + threadIdx.x;
    if (e >= E) return;

    const uint4* ra = reinterpret_cast<const uint4*>(P + (size_t)src[e] * 128);
    const uint4* rb = reinterpret_cast<const uint4*>(P + (size_t)dst[e] * 128 + 64);

    uint4 A[4], B[4];
    #pragma unroll
    for (int g = 0; g < 4; ++g) { A[g] = ra[g]; B[g] = rb[g]; }

    float sw = b2[0];
    #pragma unroll
    for (int g = 0; g < 4; ++g) {
        union { uint4 v; unsigned w[4]; } ua, ub;
        ua.v = A[g]; ub.v = B[g];
        #pragma unroll
        for (int w = 0; w < 4; ++w) {
            unsigned wa = ua.w[w], wb = ub.w[w];
            int j = g * 16 + w * 4;
            float h0 = e5((unsigned short)((wa << 8) & 0xFF00u))
                     + e5((unsigned short)((wb << 8) & 0xFF00u)) + cnode[j + 0];
            float h1 = e5((unsigned short)(wa & 0xFF00u))
                     + e5((unsigned short)(wb & 0xFF00u)) + cnode[j + 1];
            float h2 = e5((unsigned short)((wa >> 8) & 0xFF00u))
                     + e5((unsigned short)((wb >> 8) & 0xFF00u)) + cnode[j + 2];
            float h3 = e5((unsigned short)((wa >> 16) & 0xFF00u))
                     + e5((unsigned short)((wb >> 16) & 0xFF00u)) + cnode[j + 3];
            sw = fmaf(fmaxf(h0, 0.f), W2[j + 0], sw);
            sw = fmaf(fmaxf(h1, 0.f), W2[j + 1], sw);
            sw = fmaf(fmaxf(h2, 0.f), W2[j + 2], sw);
            sw = fmaf(fmaxf(h3, 0.f), W2[j + 3], sw);
        }
    }

    float uu  = u[e];
    float eps = 0.9999f - 0.9998f * uu;          // (bias-(1-bias))*u + (1-bias)
    float gate = logf(eps) - log1pf(-eps);
    float x = (gate + sw) * 0.2f;                // / TEMP
    out[e] = 1.f / (1.f + expf(-x));
}

extern "C" void kernel_launch(void* const* d_in, const int* in_sizes, int n_in,
                              void* d_out, int out_size, void* d_ws, size_t ws_size,
                              hipStream_t stream) {
    const float* embeds = (const float*)d_in[0];
    const float* W1     = (const float*)d_in[1];
    const float* b1     = (const float*)d_in[2];
    const float* W2     = (const float*)d_in[3];
    const float* b2     = (const float*)d_in[4];
    const float* u      = (const float*)d_in[5];
    const int*   src    = (const int*)d_in[6];
    const int*   dst    = (const int*)d_in[7];
    const int*   nidx   = (const int*)d_in[8];

    int E = in_sizes[6];
    int N = in_sizes[0] / D;
    int NTILES = (N + 15) / 16;

    // ws: bfrag 16384 bf16 (32KB) | cnode 64 f32 | P [N][128] u8 (6.4MB)
    unsigned short* bfrag = (unsigned short*)d_ws;
    float* cnode = (float*)(bfrag + 16384);
    unsigned char* P = (unsigned char*)(cnode + 64);

    pg_prep<<<1, 256, 0, stream>>>(embeds, W1, b1, nidx, bfrag, cnode);
    pg_nodes<<<(NTILES + 3) / 4, 256, 0, stream>>>(embeds, bfrag, P, N, NTILES);
    pg_edge<<<(E + 255) / 256, 256, 0, stream>>>(P, cnode, W2, b2, u,
                                                 src, dst, (float*)d_out, E);
}

// Round 7
// 45.076 us; speedup vs baseline: 15.2562x; 1.2338x over previous
//
#include <hip/hip_runtime.h>
#include <hip/hip_bf16.h>

// PGExplainer fused edge-MLP — round 7: parallel prep + nontemporal streams.
//
// inputs (d_in order): embeds[N,128] f32, W1[384,64] f32, b1[64] f32,
//   W2[64,1] f32, b2[1] f32, u[E,1] f32, src[E] i32, dst[E] i32, n[1] i32
// out: mask[E] f32
//
// h = relu(embeds[src]@W1a + embeds[dst]@W1b + (embeds[n]@W1c + b1))
// sw = h@W2 + b2;  mask = sigmoid((gumbel(u) + sw)/TEMP)
//
// P[node][128] (1B e5m2): cols 0..63 = embeds@W1a, 64..127 = embeds@W1b.
// pg_prep: 65 blocks (was 1 — a single-CU serial ~13us bottleneck).
// pg_edge: streams (src/dst/u/out) nontemporal to keep P gather L2-resident.

#define D 128
#define HID 64

typedef __attribute__((ext_vector_type(8))) short short8;
typedef __attribute__((ext_vector_type(4))) float f32x4;

__device__ inline unsigned short f2bf(float f) {
    union { float f; unsigned int u; } x;
    x.f = f;
    unsigned int r = x.u + 0x7FFFu + ((x.u >> 16) & 1u);   // RNE
    return (unsigned short)(r >> 16);
}

// e5m2 = top byte of IEEE f16 (we control both encode and decode).
__device__ inline unsigned char f2e5(float f) {
    _Float16 h = (_Float16)f;
    unsigned short u;
    __builtin_memcpy(&u, &h, 2);
    unsigned short r = (unsigned short)(u + 0x7Fu + ((u >> 8) & 1u));  // RNE to 8b
    return (unsigned char)(r >> 8);
}
__device__ inline float e5(unsigned short hibits) {   // hibits = byte<<8
    _Float16 h;
    __builtin_memcpy(&h, &hibits, 2);
    return (float)h;
}

// --- prep: build fragment-ordered B table (bf16) + cnode[64] ---
// bfrag[((ks*8+ct)*64+lane)*8+j] = Wcomb[k=ks*32+(lane>>4)*8+j][col=ct*16+(lane&15)]
// Wcomb[k][col] = col<64 ? W1[k][col] : W1[128+k][col-64]
__global__ __launch_bounds__(256) void pg_prep(
    const float* __restrict__ embeds, const float* __restrict__ W1,
    const float* __restrict__ b1, const int* __restrict__ nidx,
    unsigned short* __restrict__ bfrag, float* __restrict__ cnode)
{
    int t = threadIdx.x;
    if (blockIdx.x < 64) {
        int i    = blockIdx.x * 256 + t;
        int j    = i & 7;
        int lane = (i >> 3) & 63;
        int ct   = (i >> 9) & 7;
        int ks   = i >> 12;
        int k    = ks * 32 + (lane >> 4) * 8 + j;
        int col  = ct * 16 + (lane & 15);
        float w  = (col < HID) ? W1[k * HID + col]
                               : W1[(D + k) * HID + (col - HID)];
        bfrag[i] = f2bf(w);
    } else if (t < HID) {
        int n = nidx[0];
        const float* nr = embeds + (size_t)n * D;
        float c = b1[t];
        #pragma unroll 8
        for (int k = 0; k < D; ++k)
            c = fmaf(nr[k], W1[(2 * D + k) * HID + t], c);
        cnode[t] = c;
    }
}

// --- node projections via MFMA: P[node][128] e5m2 ---
__global__ __launch_bounds__(256) void pg_nodes(
    const float* __restrict__ embeds, const unsigned short* __restrict__ bfrag,
    unsigned char* __restrict__ P, int N, int NTILES)
{
    __shared__ short wl[16384];                       // 32 KiB B-frag table
    {
        const uint4* s = reinterpret_cast<const uint4*>(bfrag);
        uint4* d = reinterpret_cast<uint4*>(wl);
        #pragma unroll
        for (int i = 0; i < 8; ++i)                   // 2048 uint4 total
            d[threadIdx.x + i * 256] = s[threadIdx.x + i * 256];
    }
    __syncthreads();

    int wave  = threadIdx.x >> 6;
    int lane  = threadIdx.x & 63;
    int ntile = blockIdx.x * 4 + wave;
    if (ntile >= NTILES) return;

    int kg = lane >> 4;                               // 0..3 k-group
    int nr = ntile * 16 + (lane & 15);                // A row (node)
    if (nr >= N) nr = N - 1;
    const float* row = embeds + (size_t)nr * D + kg * 8;

    // A fragments: af[ks][j] = bf16(embeds[nr][ks*32 + kg*8 + j])
    short8 af[4];
    #pragma unroll
    for (int ks = 0; ks < 4; ++ks) {
        float4 v0 = *reinterpret_cast<const float4*>(row + ks * 32);
        float4 v1 = *reinterpret_cast<const float4*>(row + ks * 32 + 4);
        union { float f; unsigned u; } c[8];
        c[0].f = v0.x; c[1].f = v0.y; c[2].f = v0.z; c[3].f = v0.w;
        c[4].f = v1.x; c[5].f = v1.y; c[6].f = v1.z; c[7].f = v1.w;
        union { unsigned u[4]; short8 s; } pk;
        #pragma unroll
        for (int p = 0; p < 4; ++p)                   // truncate-pack 2 f32 -> u32
            pk.u[p] = (c[2 * p + 1].u & 0xFFFF0000u) | (c[2 * p].u >> 16);
        af[ks] = pk.s;
    }

    const short8* wl8 = reinterpret_cast<const short8*>(wl);

    f32x4 acc[8];
    #pragma unroll
    for (int ct = 0; ct < 8; ++ct) acc[ct] = (f32x4){0.f, 0.f, 0.f, 0.f};

    #pragma unroll
    for (int ct = 0; ct < 8; ++ct) {
        #pragma unroll
        for (int ks = 0; ks < 4; ++ks) {
            short8 bf = wl8[(ks * 8 + ct) * 64 + lane];
            acc[ct] = __builtin_amdgcn_mfma_f32_16x16x32_bf16(af[ks], bf, acc[ct], 0, 0, 0);
        }
    }

    // C layout: col = ct*16 + (lane&15), row(node) = ntile*16 + (lane>>4)*4 + reg
    int node0 = ntile * 16 + kg * 4;
    #pragma unroll
    for (int ct = 0; ct < 8; ++ct) {
        int col = ct * 16 + (lane & 15);
        #pragma unroll
        for (int r = 0; r < 4; ++r) {
            int node = node0 + r;
            if (node < N)
                P[(size_t)node * 128 + col] = f2e5(acc[ct][r]);
        }
    }
}

// --- per-edge: gather 64B src + 64B dst, decode e5m2, relu-dot, gumbel ---
__global__ __launch_bounds__(256) void pg_edge(
    const unsigned char* __restrict__ P,
    const float* __restrict__ cnode, const float* __restrict__ W2,
    const float* __restrict__ b2, const float* __restrict__ u,
    const int* __restrict__ src, const int* __restrict__ dst,
    float* __restrict__ out, int E)
{
    int e = blockIdx.x * 256 + threadIdx.x;
    if (e >= E) return;

    int se = __builtin_nontemporal_load(src + e);
    int de = __builtin_nontemporal_load(dst + e);
    float uu = __builtin_nontemporal_load(u + e);

    const uint4* ra = reinterpret_cast<const uint4*>(P + (size_t)se * 128);
    const uint4* rb = reinterpret_cast<const uint4*>(P + (size_t)de * 128 + 64);

    uint4 A[4], B[4];
    #pragma unroll
    for (int g = 0; g < 4; ++g) { A[g] = ra[g]; B[g] = rb[g]; }

    float sw = b2[0];
    #pragma unroll
    for (int g = 0; g < 4; ++g) {
        union { uint4 v; unsigned w[4]; } ua, ub;
        ua.v = A[g]; ub.v = B[g];
        #pragma unroll
        for (int w = 0; w < 4; ++w) {
            unsigned wa = ua.w[w], wb = ub.w[w];
            int j = g * 16 + w * 4;
            float h0 = e5((unsigned short)((wa << 8) & 0xFF00u))
                     + e5((unsigned short)((wb << 8) & 0xFF00u)) + cnode[j + 0];
            float h1 = e5((unsigned short)(wa & 0xFF00u))
                     + e5((unsigned short)(wb & 0xFF00u)) + cnode[j + 1];
            float h2 = e5((unsigned short)((wa >> 8) & 0xFF00u))
                     + e5((unsigned short)((wb >> 8) & 0xFF00u)) + cnode[j + 2];
            float h3 = e5((unsigned short)((wa >> 16) & 0xFF00u))
                     + e5((unsigned short)((wb >> 16) & 0xFF00u)) + cnode[j + 3];
            sw = fmaf(fmaxf(h0, 0.f), W2[j + 0], sw);
            sw = fmaf(fmaxf(h1, 0.f), W2[j + 1], sw);
            sw = fmaf(fmaxf(h2, 0.f), W2[j + 2], sw);
            sw = fmaf(fmaxf(h3, 0.f), W2[j + 3], sw);
        }
    }

    float eps = 0.9999f - 0.9998f * uu;          // (bias-(1-bias))*u + (1-bias)
    float gate = logf(eps) - log1pf(-eps);
    float x = (gate + sw) * 0.2f;                // / TEMP
    __builtin_nontemporal_store(1.f / (1.f + expf(-x)), out + e);
}

extern "C" void kernel_launch(void* const* d_in, const int* in_sizes, int n_in,
                              void* d_out, int out_size, void* d_ws, size_t ws_size,
                              hipStream_t stream) {
    const float* embeds = (const float*)d_in[0];
    const float* W1     = (const float*)d_in[1];
    const float* b1     = (const float*)d_in[2];
    const float* W2     = (const float*)d_in[3];
    const float* b2     = (const float*)d_in[4];
    const float* u      = (const float*)d_in[5];
    const int*   src    = (const int*)d_in[6];
    const int*   dst    = (const int*)d_in[7];
    const int*   nidx   = (const int*)d_in[8];

    int E = in_sizes[6];
    int N = in_sizes[0] / D;
    int NTILES = (N + 15) / 16;

    // ws: bfrag 16384 bf16 (32KB) | cnode 64 f32 | P [N][128] u8 (6.4MB)
    unsigned short* bfrag = (unsigned short*)d_ws;
    float* cnode = (float*)(bfrag + 16384);
    unsigned char* P = (unsigned char*)(cnode + 64);

    pg_prep<<<65, 256, 0, stream>>>(embeds, W1, b1, nidx, bfrag, cnode);
    pg_nodes<<<(NTILES + 3) / 4, 256, 0, stream>>>(embeds, bfrag, P, N, NTILES);
    pg_edge<<<(E + 255) / 256, 256, 0, stream>>>(P, cnode, W2, b2, u,
                                                 src, dst, (float*)d_out, E);
}

// Round 8
// 44.355 us; speedup vs baseline: 15.5039x; 1.0162x over previous
//
#include <hip/hip_runtime.h>
#include <hip/hip_bf16.h>

// PGExplainer fused edge-MLP — round 8: coalesced P stores in pg_nodes.
//
// inputs (d_in order): embeds[N,128] f32, W1[384,64] f32, b1[64] f32,
//   W2[64,1] f32, b2[1] f32, u[E,1] f32, src[E] i32, dst[E] i32, n[1] i32
// out: mask[E] f32
//
// h = relu(embeds[src]@W1a + embeds[dst]@W1b + (embeds[n]@W1c + b1))
// sw = h@W2 + b2;  mask = sigmoid((gumbel(u) + sw)/TEMP)
//
// P[node][128] (1B e5m2): cols 0..63 = embeds@W1a, 64..127 = embeds@W1b.
// pg_nodes: SWAPPED mfma (W as A-operand) => reg index = consecutive W-cols
// -> pack 4 bytes/u32 -> LDS tile [16][144] -> coalesced dwordx4 stores
// (was 2048 scattered byte-stores per wave = the hidden 10-15us).

#define D 128
#define HID 64

typedef __attribute__((ext_vector_type(8))) short short8;
typedef __attribute__((ext_vector_type(4))) float f32x4;

__device__ inline unsigned short f2bf(float f) {
    union { float f; unsigned int u; } x;
    x.f = f;
    unsigned int r = x.u + 0x7FFFu + ((x.u >> 16) & 1u);   // RNE
    return (unsigned short)(r >> 16);
}

// e5m2 = top byte of IEEE f16 (we control both encode and decode).
__device__ inline unsigned int f2e5u(float f) {        // returns byte in [0,255]
    _Float16 h = (_Float16)f;
    unsigned short u;
    __builtin_memcpy(&u, &h, 2);
    unsigned short r = (unsigned short)(u + 0x7Fu + ((u >> 8) & 1u));  // RNE to 8b
    return (unsigned int)(r >> 8) & 0xFFu;
}
__device__ inline float e5(unsigned short hibits) {   // hibits = byte<<8
    _Float16 h;
    __builtin_memcpy(&h, &hibits, 2);
    return (float)h;
}

// --- prep: build fragment-ordered W table (bf16) + cnode[64] ---
// bfrag[((ks*8+ct)*64+lane)*8+j] = Wcomb[k=ks*32+(lane>>4)*8+j][col=ct*16+(lane&15)]
// Wcomb[k][col] = col<64 ? W1[k][col] : W1[128+k][col-64]
__global__ __launch_bounds__(256) void pg_prep(
    const float* __restrict__ embeds, const float* __restrict__ W1,
    const float* __restrict__ b1, const int* __restrict__ nidx,
    unsigned short* __restrict__ bfrag, float* __restrict__ cnode)
{
    int t = threadIdx.x;
    if (blockIdx.x < 64) {
        int i    = blockIdx.x * 256 + t;
        int j    = i & 7;
        int lane = (i >> 3) & 63;
        int ct   = (i >> 9) & 7;
        int ks   = i >> 12;
        int k    = ks * 32 + (lane >> 4) * 8 + j;
        int col  = ct * 16 + (lane & 15);
        float w  = (col < HID) ? W1[k * HID + col]
                               : W1[(D + k) * HID + (col - HID)];
        bfrag[i] = f2bf(w);
    } else if (t < HID) {
        int n = nidx[0];
        const float* nr = embeds + (size_t)n * D;
        float c = b1[t];
        #pragma unroll 8
        for (int k = 0; k < D; ++k)
            c = fmaf(nr[k], W1[(2 * D + k) * HID + t], c);
        cnode[t] = c;
    }
}

// --- node projections via MFMA: P[node][128] e5m2, coalesced stores ---
__global__ __launch_bounds__(256) void pg_nodes(
    const float* __restrict__ embeds, const unsigned short* __restrict__ bfrag,
    unsigned char* __restrict__ P, int N, int NTILES)
{
    __shared__ short wl[16384];                       // 32 KiB W-frag table
    __shared__ unsigned char st[4][16 * 144];         // 9 KiB store staging
    {
        const uint4* s = reinterpret_cast<const uint4*>(bfrag);
        uint4* d = reinterpret_cast<uint4*>(wl);
        #pragma unroll
        for (int i = 0; i < 8; ++i)                   // 2048 uint4 total
            d[threadIdx.x + i * 256] = s[threadIdx.x + i * 256];
    }
    __syncthreads();

    int wave  = threadIdx.x >> 6;
    int lane  = threadIdx.x & 63;
    int ntile = blockIdx.x * 4 + wave;
    bool active = (ntile < NTILES);

    int kg = lane >> 4;                               // 0..3 k-group
    if (active) {
        int nr = ntile * 16 + (lane & 15);            // node (B-operand col)
        if (nr >= N) nr = N - 1;
        const float* row = embeds + (size_t)nr * D + kg * 8;

        // emb fragments: af[ks][j] = bf16(embeds[nr][ks*32 + kg*8 + j])
        short8 af[4];
        #pragma unroll
        for (int ks = 0; ks < 4; ++ks) {
            float4 v0 = *reinterpret_cast<const float4*>(row + ks * 32);
            float4 v1 = *reinterpret_cast<const float4*>(row + ks * 32 + 4);
            union { float f; unsigned u; } c[8];
            c[0].f = v0.x; c[1].f = v0.y; c[2].f = v0.z; c[3].f = v0.w;
            c[4].f = v1.x; c[5].f = v1.y; c[6].f = v1.z; c[7].f = v1.w;
            union { unsigned u[4]; short8 s; } pk;
            #pragma unroll
            for (int p = 0; p < 4; ++p)               // truncate-pack 2 f32 -> u32
                pk.u[p] = (c[2 * p + 1].u & 0xFFFF0000u) | (c[2 * p].u >> 16);
            af[ks] = pk.s;
        }

        const short8* wl8 = reinterpret_cast<const short8*>(wl);

        f32x4 acc[8];
        #pragma unroll
        for (int ct = 0; ct < 8; ++ct) acc[ct] = (f32x4){0.f, 0.f, 0.f, 0.f};

        // SWAPPED operands: D = W^T_tile * emb^T_tile -> D[wcol][node]
        #pragma unroll
        for (int ct = 0; ct < 8; ++ct) {
            #pragma unroll
            for (int ks = 0; ks < 4; ++ks) {
                short8 wf = wl8[(ks * 8 + ct) * 64 + lane];
                acc[ct] = __builtin_amdgcn_mfma_f32_16x16x32_bf16(wf, af[ks], acc[ct], 0, 0, 0);
            }
        }

        // lane holds: node = lane&15, wcols = ct*16 + kg*4 + r (r=0..3 consecutive)
        // pack 4 bytes -> u32, stage in LDS tile [node][col]
        #pragma unroll
        for (int ct = 0; ct < 8; ++ct) {
            unsigned w = f2e5u(acc[ct][0])
                       | (f2e5u(acc[ct][1]) << 8)
                       | (f2e5u(acc[ct][2]) << 16)
                       | (f2e5u(acc[ct][3]) << 24);
            *reinterpret_cast<unsigned*>(&st[wave][(lane & 15) * 144 + ct * 16 + kg * 4]) = w;
        }
    }
    __syncthreads();

    if (active) {
        // coalesced readout: 128 chunks of 16B; lane does chunks {lane, lane+64}
        #pragma unroll
        for (int h = 0; h < 2; ++h) {
            int c   = lane + h * 64;
            int nr  = c >> 3;                          // 0..15
            int off = (c & 7) * 16;                    // 0..112
            uint4 v = *reinterpret_cast<const uint4*>(&st[wave][nr * 144 + off]);
            int node = ntile * 16 + nr;
            if (node < N)
                *reinterpret_cast<uint4*>(P + (size_t)node * 128 + off) = v;
        }
    }
}

// --- per-edge: gather 64B src + 64B dst, decode e5m2, relu-dot, gumbel ---
__global__ __launch_bounds__(256) void pg_edge(
    const unsigned char* __restrict__ P,
    const float* __restrict__ cnode, const float* __restrict__ W2,
    const float* __restrict__ b2, const float* __restrict__ u,
    const int* __restrict__ src, const int* __restrict__ dst,
    float* __restrict__ out, int E)
{
    int e = blockIdx.x * 256 + threadIdx.x;
    if (e >= E) return;

    int se = __builtin_nontemporal_load(src + e);
    int de = __builtin_nontemporal_load(dst + e);
    float uu = __builtin_nontemporal_load(u + e);

    const uint4* ra = reinterpret_cast<const uint4*>(P + (size_t)se * 128);
    const uint4* rb = reinterpret_cast<const uint4*>(P + (size_t)de * 128 + 64);

    uint4 A[4], B[4];
    #pragma unroll
    for (int g = 0; g < 4; ++g) { A[g] = ra[g]; B[g] = rb[g]; }

    float sw = b2[0];
    #pragma unroll
    for (int g = 0; g < 4; ++g) {
        union { uint4 v; unsigned w[4]; } ua, ub;
        ua.v = A[g]; ub.v = B[g];
        #pragma unroll
        for (int w = 0; w < 4; ++w) {
            unsigned wa = ua.w[w], wb = ub.w[w];
            int j = g * 16 + w * 4;
            float h0 = e5((unsigned short)((wa << 8) & 0xFF00u))
                     + e5((unsigned short)((wb << 8) & 0xFF00u)) + cnode[j + 0];
            float h1 = e5((unsigned short)(wa & 0xFF00u))
                     + e5((unsigned short)(wb & 0xFF00u)) + cnode[j + 1];
            float h2 = e5((unsigned short)((wa >> 8) & 0xFF00u))
                     + e5((unsigned short)((wb >> 8) & 0xFF00u)) + cnode[j + 2];
            float h3 = e5((unsigned short)((wa >> 16) & 0xFF00u))
                     + e5((unsigned short)((wb >> 16) & 0xFF00u)) + cnode[j + 3];
            sw = fmaf(fmaxf(h0, 0.f), W2[j + 0], sw);
            sw = fmaf(fmaxf(h1, 0.f), W2[j + 1], sw);
            sw = fmaf(fmaxf(h2, 0.f), W2[j + 2], sw);
            sw = fmaf(fmaxf(h3, 0.f), W2[j + 3], sw);
        }
    }

    float eps = 0.9999f - 0.9998f * uu;          // (bias-(1-bias))*u + (1-bias)
    float gate = logf(eps) - log1pf(-eps);
    float x = (gate + sw) * 0.2f;                // / TEMP
    __builtin_nontemporal_store(1.f / (1.f + expf(-x)), out + e);
}

extern "C" void kernel_launch(void* const* d_in, const int* in_sizes, int n_in,
                              void* d_out, int out_size, void* d_ws, size_t ws_size,
                              hipStream_t stream) {
    const float* embeds = (const float*)d_in[0];
    const float* W1     = (const float*)d_in[1];
    const float* b1     = (const float*)d_in[2];
    const float* W2     = (const float*)d_in[3];
    const float* b2     = (const float*)d_in[4];
    const float* u      = (const float*)d_in[5];
    const int*   src    = (const int*)d_in[6];
    const int*   dst    = (const int*)d_in[7];
    const int*   nidx   = (const int*)d_in[8];

    int E = in_sizes[6];
    int N = in_sizes[0] / D;
    int NTILES = (N + 15) / 16;

    // ws: bfrag 16384 bf16 (32KB) | cnode 64 f32 | P [N][128] u8 (6.4MB)
    unsigned short* bfrag = (unsigned short*)d_ws;
    float* cnode = (float*)(bfrag + 16384);
    unsigned char* P = (unsigned char*)(cnode + 64);

    pg_prep<<<65, 256, 0, stream>>>(embeds, W1, b1, nidx, bfrag, cnode);
    pg_nodes<<<(NTILES + 3) / 4, 256, 0, stream>>>(embeds, bfrag, P, N, NTILES);
    pg_edge<<<(E + 255) / 256, 256, 0, stream>>>(P, cnode, W2, b2, u,
                                                 src, dst, (float*)d_out, E);
}

// Round 9
// 42.115 us; speedup vs baseline: 16.3286x; 1.0532x over previous
//
#include <hip/hip_runtime.h>
#include <hip/hip_bf16.h>
#include <string.h>

// PGExplainer fused edge-MLP — round 9: barrier-free nodes + packed-f16 edge.
//
// inputs (d_in order): embeds[N,128] f32, W1[384,64] f32, b1[64] f32,
//   W2[64,1] f32, b2[1] f32, u[E,1] f32, src[E] i32, dst[E] i32, n[1] i32
// out: mask[E] f32
//
// h = relu(embeds[src]@W1a + embeds[dst]@W1b + (embeds[n]@W1c + b1))
// sw = h@W2 + b2;  mask = sigmoid((gumbel(u) + sw)/TEMP)
//
// P[node][128] (1B e5m2 = f16 top byte): cols 0..63 = @W1a, 64..127 = @W1b.
// pg_nodes: W-frags read direct from global (32KB, L1/L2-hot) — no block
//   staging, no barriers; per-wave LDS tile only for coalesced P stores.
// pg_edge: 2 edges/thread; e5m2 pairs decoded by mask into f16x2;
//   v_pk_add_f16 + v_pk_max_f16 + v_dot2_f32_f16 datapath.

#define D 128
#define HID 64

typedef __attribute__((ext_vector_type(8))) short short8;
typedef __attribute__((ext_vector_type(4))) float f32x4;
typedef _Float16 h2 __attribute__((ext_vector_type(2)));

union U32H2 { unsigned u; h2 h; };

__device__ inline unsigned short f2bf(float f) {
    union { float f; unsigned int u; } x;
    x.f = f;
    unsigned int r = x.u + 0x7FFFu + ((x.u >> 16) & 1u);   // RNE
    return (unsigned short)(r >> 16);
}

// e5m2 = top byte of IEEE f16 (we control both encode and decode).
__device__ inline unsigned int f2e5u(float f) {        // returns byte in [0,255]
    _Float16 h = (_Float16)f;
    unsigned short u;
    __builtin_memcpy(&u, &h, 2);
    unsigned short r = (unsigned short)(u + 0x7Fu + ((u >> 8) & 1u));  // RNE to 8b
    return (unsigned int)(r >> 8) & 0xFFu;
}

__device__ inline unsigned packh(float lo, float hi) {
    _Float16 l = (_Float16)lo, h = (_Float16)hi;
    unsigned short ul, uh;
    __builtin_memcpy(&ul, &l, 2);
    __builtin_memcpy(&uh, &h, 2);
    return (unsigned)ul | ((unsigned)uh << 16);
}

__device__ inline h2 relu2(h2 x) {
#if __has_builtin(__builtin_elementwise_max)
    return __builtin_elementwise_max(x, (h2)((_Float16)0));
#else
    h2 r;
    r[0] = x[0] > (_Float16)0 ? x[0] : (_Float16)0;
    r[1] = x[1] > (_Float16)0 ? x[1] : (_Float16)0;
    return r;
#endif
}

__device__ inline float dot2acc(h2 a, h2 b, float c) {
#if __has_builtin(__builtin_amdgcn_fdot2)
    return __builtin_amdgcn_fdot2(a, b, c, false);
#else
    c = fmaf((float)a[0], (float)b[0], c);
    return fmaf((float)a[1], (float)b[1], c);
#endif
}

// --- prep: fragment-ordered W table (bf16) + packed cnode/W2 pair tables ---
// bfrag[((ks*8+ct)*64+lane)*8+j] = Wcomb[k=ks*32+(lane>>4)*8+j][col=ct*16+(lane&15)]
// Wcomb[k][col] = col<64 ? W1[k][col] : W1[128+k][col-64]
// cnodeh[2*wi+sub] = f16pair(c[4wi+sub], c[4wi+sub+2]); same for w2h with W2.
__global__ __launch_bounds__(256) void pg_prep(
    const float* __restrict__ embeds, const float* __restrict__ W1,
    const float* __restrict__ b1, const float* __restrict__ W2,
    const int* __restrict__ nidx,
    unsigned short* __restrict__ bfrag,
    unsigned* __restrict__ cnodeh, unsigned* __restrict__ w2h)
{
    int t = threadIdx.x;
    if (blockIdx.x < 64) {
        int i    = blockIdx.x * 256 + t;
        int j    = i & 7;
        int lane = (i >> 3) & 63;
        int ct   = (i >> 9) & 7;
        int ks   = i >> 12;
        int k    = ks * 32 + (lane >> 4) * 8 + j;
        int col  = ct * 16 + (lane & 15);
        float w  = (col < HID) ? W1[k * HID + col]
                               : W1[(D + k) * HID + (col - HID)];
        bfrag[i] = f2bf(w);
    } else {
        __shared__ float cs[HID];
        if (t < HID) {
            int n = nidx[0];
            const float* nr = embeds + (size_t)n * D;
            float c = b1[t];
            #pragma unroll 8
            for (int k = 0; k < D; ++k)
                c = fmaf(nr[k], W1[(2 * D + k) * HID + t], c);
            cs[t] = c;
        }
        __syncthreads();
        if (t < 32) {
            int wi = t >> 1, sub = t & 1;
            int j = 4 * wi + sub;
            cnodeh[t] = packh(cs[j], cs[j + 2]);
            w2h[t]    = packh(W2[j], W2[j + 2]);
        }
    }
}

// --- node projections via MFMA: P[node][128] e5m2, barrier-free ---
__global__ __launch_bounds__(256) void pg_nodes(
    const float* __restrict__ embeds, const unsigned short* __restrict__ bfrag,
    unsigned char* __restrict__ P, int N, int NTILES)
{
    __shared__ unsigned char st[4][16 * 144];         // 9 KiB per-wave staging

    int wave  = threadIdx.x >> 6;
    int lane  = threadIdx.x & 63;
    int ntile = blockIdx.x * 4 + wave;
    if (ntile >= NTILES) return;

    int kg = lane >> 4;                               // 0..3 k-group
    int nr = ntile * 16 + (lane & 15);                // node (B-operand col)
    if (nr >= N) nr = N - 1;
    const float* row = embeds + (size_t)nr * D + kg * 8;

    // emb fragments: af[ks][j] = bf16(embeds[nr][ks*32 + kg*8 + j])
    short8 af[4];
    #pragma unroll
    for (int ks = 0; ks < 4; ++ks) {
        float4 v0 = *reinterpret_cast<const float4*>(row + ks * 32);
        float4 v1 = *reinterpret_cast<const float4*>(row + ks * 32 + 4);
        union { float f; unsigned u; } c[8];
        c[0].f = v0.x; c[1].f = v0.y; c[2].f = v0.z; c[3].f = v0.w;
        c[4].f = v1.x; c[5].f = v1.y; c[6].f = v1.z; c[7].f = v1.w;
        union { unsigned u[4]; short8 s; } pk;
        #pragma unroll
        for (int p = 0; p < 4; ++p)                   // truncate-pack 2 f32 -> u32
            pk.u[p] = (c[2 * p + 1].u & 0xFFFF0000u) | (c[2 * p].u >> 16);
        af[ks] = pk.s;
    }

    const short8* gw = reinterpret_cast<const short8*>(bfrag);

    f32x4 acc[8];
    #pragma unroll
    for (int ct = 0; ct < 8; ++ct) acc[ct] = (f32x4){0.f, 0.f, 0.f, 0.f};

    // SWAPPED operands: D = W^T_tile * emb^T_tile -> D[wcol][node]
    #pragma unroll
    for (int ct = 0; ct < 8; ++ct) {
        #pragma unroll
        for (int ks = 0; ks < 4; ++ks) {
            short8 wf = gw[(ks * 8 + ct) * 64 + lane];
            acc[ct] = __builtin_amdgcn_mfma_f32_16x16x32_bf16(wf, af[ks], acc[ct], 0, 0, 0);
        }
    }

    // lane holds: node = lane&15, wcols = ct*16 + kg*4 + r (r=0..3 consecutive)
    #pragma unroll
    for (int ct = 0; ct < 8; ++ct) {
        unsigned w = f2e5u(acc[ct][0])
                   | (f2e5u(acc[ct][1]) << 8)
                   | (f2e5u(acc[ct][2]) << 16)
                   | (f2e5u(acc[ct][3]) << 24);
        *reinterpret_cast<unsigned*>(&st[wave][(lane & 15) * 144 + ct * 16 + kg * 4]) = w;
    }
    // same-wave LDS RAW -> compiler inserts lgkmcnt wait; no barrier needed
    #pragma unroll
    for (int h = 0; h < 2; ++h) {
        int c   = lane + h * 64;
        int r   = c >> 3;                              // 0..15
        int off = (c & 7) * 16;                        // 0..112
        uint4 v = *reinterpret_cast<const uint4*>(&st[wave][r * 144 + off]);
        int node = ntile * 16 + r;
        if (node < N)
            *reinterpret_cast<uint4*>(P + (size_t)node * 128 + off) = v;
    }
}

// --- per-edge MLP in packed f16 ---
__device__ inline float mlp_sw(const uint4 A[4], const uint4 B[4],
                               const unsigned* __restrict__ cn,
                               const unsigned* __restrict__ w2, float sw)
{
    #pragma unroll
    for (int g = 0; g < 4; ++g) {
        unsigned aw[4] = {A[g].x, A[g].y, A[g].z, A[g].w};
        unsigned bw[4] = {B[g].x, B[g].y, B[g].z, B[g].w};
        #pragma unroll
        for (int w = 0; w < 4; ++w) {
            int wi = g * 4 + w;                        // word 0..15
            U32H2 a0, a1, b0, b1, c0, c1, W0, W1v;
            a0.u = (aw[w] << 8) & 0xFF00FF00u;         // units (4wi, 4wi+2)
            a1.u =  aw[w]       & 0xFF00FF00u;         // units (4wi+1, 4wi+3)
            b0.u = (bw[w] << 8) & 0xFF00FF00u;
            b1.u =  bw[w]       & 0xFF00FF00u;
            c0.u = cn[2 * wi];     c1.u = cn[2 * wi + 1];
            W0.u = w2[2 * wi];     W1v.u = w2[2 * wi + 1];
            h2 h0 = relu2(a0.h + b0.h + c0.h);
            h2 h1 = relu2(a1.h + b1.h + c1.h);
            sw = dot2acc(h0, W0.h, sw);
            sw = dot2acc(h1, W1v.h, sw);
        }
    }
    return sw;
}

__device__ inline float gumbel_sigmoid(float uu, float sw) {
    float a = 0.9999f - 0.9998f * uu;                  // eps
    float b = 0.0001f + 0.9998f * uu;                  // 1-eps (exact form)
    float gate = __logf(__fdividef(a, b));
    float x = (gate + sw) * 0.2f;                      // / TEMP
    return __fdividef(1.f, 1.f + __expf(-x));
}

// --- per-edge: 2 edges/thread; gather 4x64B; packed-f16 MLP; gumbel ---
__global__ __launch_bounds__(256) void pg_edge(
    const unsigned char* __restrict__ P,
    const unsigned* __restrict__ cnodeh, const unsigned* __restrict__ w2h,
    const float* __restrict__ b2, const float* __restrict__ u,
    const int* __restrict__ src, const int* __restrict__ dst,
    float* __restrict__ out, int E)
{
    int p  = blockIdx.x * 256 + threadIdx.x;
    int e0 = p * 2;
    if (e0 >= E) return;
    bool two = (e0 + 1 < E);

    int s0, s1, d0, d1;
    float u0, u1;
    if (two) {
        int2 sv = *reinterpret_cast<const int2*>(src + e0);
        int2 dv = *reinterpret_cast<const int2*>(dst + e0);
        float2 uv = *reinterpret_cast<const float2*>(u + e0);
        s0 = sv.x; s1 = sv.y; d0 = dv.x; d1 = dv.y; u0 = uv.x; u1 = uv.y;
    } else {
        s0 = s1 = src[e0]; d0 = d1 = dst[e0]; u0 = u1 = u[e0];
    }

    const uint4* ra0 = reinterpret_cast<const uint4*>(P + (size_t)s0 * 128);
    const uint4* rb0 = reinterpret_cast<const uint4*>(P + (size_t)d0 * 128 + 64);
    const uint4* ra1 = reinterpret_cast<const uint4*>(P + (size_t)s1 * 128);
    const uint4* rb1 = reinterpret_cast<const uint4*>(P + (size_t)d1 * 128 + 64);

    uint4 A0[4], B0[4], A1[4], B1[4];
    #pragma unroll
    for (int g = 0; g < 4; ++g) { A0[g] = ra0[g]; B0[g] = rb0[g]; }
    #pragma unroll
    for (int g = 0; g < 4; ++g) { A1[g] = ra1[g]; B1[g] = rb1[g]; }

    float swi = b2[0];
    float sw0 = mlp_sw(A0, B0, cnodeh, w2h, swi);
    float sw1 = mlp_sw(A1, B1, cnodeh, w2h, swi);

    float m0 = gumbel_sigmoid(u0, sw0);
    float m1 = gumbel_sigmoid(u1, sw1);

    if (two) {
        float2 o = {m0, m1};
        *reinterpret_cast<float2*>(out + e0) = o;
    } else {
        out[e0] = m0;
    }
}

extern "C" void kernel_launch(void* const* d_in, const int* in_sizes, int n_in,
                              void* d_out, int out_size, void* d_ws, size_t ws_size,
                              hipStream_t stream) {
    const float* embeds = (const float*)d_in[0];
    const float* W1     = (const float*)d_in[1];
    const float* b1     = (const float*)d_in[2];
    const float* W2     = (const float*)d_in[3];
    const float* b2     = (const float*)d_in[4];
    const float* u      = (const float*)d_in[5];
    const int*   src    = (const int*)d_in[6];
    const int*   dst    = (const int*)d_in[7];
    const int*   nidx   = (const int*)d_in[8];

    int E = in_sizes[6];
    int N = in_sizes[0] / D;
    int NTILES = (N + 15) / 16;

    // ws: bfrag 16384 bf16 (32KB) | cnodeh 32 u32 | w2h 32 u32 | P [N][128] u8
    unsigned short* bfrag = (unsigned short*)d_ws;
    unsigned* cnodeh = (unsigned*)(bfrag + 16384);
    unsigned* w2h    = cnodeh + 32;
    unsigned char* P = (unsigned char*)(w2h + 32);

    pg_prep<<<65, 256, 0, stream>>>(embeds, W1, b1, W2, nidx, bfrag, cnodeh, w2h);
    pg_nodes<<<(NTILES + 3) / 4, 256, 0, stream>>>(embeds, bfrag, P, N, NTILES);

    int pairs = (E + 1) / 2;
    pg_edge<<<(pairs + 255) / 256, 256, 0, stream>>>(P, cnodeh, w2h, b2, u,
                                                     src, dst, (float*)d_out, E);
}

// Round 10
// 36.666 us; speedup vs baseline: 18.7554x; 1.1486x over previous
//
#include <hip/hip_runtime.h>
#include <hip/hip_bf16.h>
#include <string.h>

// PGExplainer fused edge-MLP — round 10: quad-cooperative edge gather.
//
// inputs (d_in order): embeds[N,128] f32, W1[384,64] f32, b1[64] f32,
//   W2[64,1] f32, b2[1] f32, u[E,1] f32, src[E] i32, dst[E] i32, n[1] i32
// out: mask[E] f32
//
// h = relu(embeds[src]@W1a + embeds[dst]@W1b + (embeds[n]@W1c + b1))
// sw = h@W2 + b2;  mask = sigmoid((gumbel(u) + sw)/TEMP)
//
// P[node][128] (1B e5m2 = f16 top byte): cols 0..63 = @W1a, 64..127 = @W1b.
// pg_edge: 4 lanes cooperate per edge -> each P-row read is ONE coalesced
//   64B transaction (was 64 divergent lane-addresses per instr). Lane r
//   covers hidden units 16r..16r+15; quad shfl_xor reduce; lane0 writes.

#define D 128
#define HID 64

typedef __attribute__((ext_vector_type(8))) short short8;
typedef __attribute__((ext_vector_type(4))) float f32x4;
typedef _Float16 h2 __attribute__((ext_vector_type(2)));

union U32H2 { unsigned u; h2 h; };

__device__ inline unsigned short f2bf(float f) {
    union { float f; unsigned int u; } x;
    x.f = f;
    unsigned int r = x.u + 0x7FFFu + ((x.u >> 16) & 1u);   // RNE
    return (unsigned short)(r >> 16);
}

// e5m2 = top byte of IEEE f16 (we control both encode and decode).
__device__ inline unsigned int f2e5u(float f) {        // returns byte in [0,255]
    _Float16 h = (_Float16)f;
    unsigned short u;
    __builtin_memcpy(&u, &h, 2);
    unsigned short r = (unsigned short)(u + 0x7Fu + ((u >> 8) & 1u));  // RNE to 8b
    return (unsigned int)(r >> 8) & 0xFFu;
}

__device__ inline unsigned packh(float lo, float hi) {
    _Float16 l = (_Float16)lo, h = (_Float16)hi;
    unsigned short ul, uh;
    __builtin_memcpy(&ul, &l, 2);
    __builtin_memcpy(&uh, &h, 2);
    return (unsigned)ul | ((unsigned)uh << 16);
}

__device__ inline h2 relu2(h2 x) {
#if __has_builtin(__builtin_elementwise_max)
    return __builtin_elementwise_max(x, (h2)((_Float16)0));
#else
    h2 r;
    r[0] = x[0] > (_Float16)0 ? x[0] : (_Float16)0;
    r[1] = x[1] > (_Float16)0 ? x[1] : (_Float16)0;
    return r;
#endif
}

__device__ inline float dot2acc(h2 a, h2 b, float c) {
#if __has_builtin(__builtin_amdgcn_fdot2)
    return __builtin_amdgcn_fdot2(a, b, c, false);
#else
    c = fmaf((float)a[0], (float)b[0], c);
    return fmaf((float)a[1], (float)b[1], c);
#endif
}

// --- prep: fragment-ordered W table (bf16) + packed cnode/W2 pair tables ---
__global__ __launch_bounds__(256) void pg_prep(
    const float* __restrict__ embeds, const float* __restrict__ W1,
    const float* __restrict__ b1, const float* __restrict__ W2,
    const int* __restrict__ nidx,
    unsigned short* __restrict__ bfrag,
    unsigned* __restrict__ cnodeh, unsigned* __restrict__ w2h)
{
    int t = threadIdx.x;
    if (blockIdx.x < 64) {
        int i    = blockIdx.x * 256 + t;
        int j    = i & 7;
        int lane = (i >> 3) & 63;
        int ct   = (i >> 9) & 7;
        int ks   = i >> 12;
        int k    = ks * 32 + (lane >> 4) * 8 + j;
        int col  = ct * 16 + (lane & 15);
        float w  = (col < HID) ? W1[k * HID + col]
                               : W1[(D + k) * HID + (col - HID)];
        bfrag[i] = f2bf(w);
    } else {
        __shared__ float cs[HID];
        if (t < HID) {
            int n = nidx[0];
            const float* nr = embeds + (size_t)n * D;
            float c = b1[t];
            #pragma unroll 8
            for (int k = 0; k < D; ++k)
                c = fmaf(nr[k], W1[(2 * D + k) * HID + t], c);
            cs[t] = c;
        }
        __syncthreads();
        if (t < 32) {
            int wi = t >> 1, sub = t & 1;
            int j = 4 * wi + sub;
            cnodeh[t] = packh(cs[j], cs[j + 2]);
            w2h[t]    = packh(W2[j], W2[j + 2]);
        }
    }
}

// --- node projections via MFMA: P[node][128] e5m2, barrier-free ---
__global__ __launch_bounds__(256) void pg_nodes(
    const float* __restrict__ embeds, const unsigned short* __restrict__ bfrag,
    unsigned char* __restrict__ P, int N, int NTILES)
{
    __shared__ unsigned char st[4][16 * 144];         // 9 KiB per-wave staging

    int wave  = threadIdx.x >> 6;
    int lane  = threadIdx.x & 63;
    int ntile = blockIdx.x * 4 + wave;
    if (ntile >= NTILES) return;

    int kg = lane >> 4;                               // 0..3 k-group
    int nr = ntile * 16 + (lane & 15);                // node (B-operand col)
    if (nr >= N) nr = N - 1;
    const float* row = embeds + (size_t)nr * D + kg * 8;

    short8 af[4];
    #pragma unroll
    for (int ks = 0; ks < 4; ++ks) {
        float4 v0 = *reinterpret_cast<const float4*>(row + ks * 32);
        float4 v1 = *reinterpret_cast<const float4*>(row + ks * 32 + 4);
        union { float f; unsigned u; } c[8];
        c[0].f = v0.x; c[1].f = v0.y; c[2].f = v0.z; c[3].f = v0.w;
        c[4].f = v1.x; c[5].f = v1.y; c[6].f = v1.z; c[7].f = v1.w;
        union { unsigned u[4]; short8 s; } pk;
        #pragma unroll
        for (int p = 0; p < 4; ++p)                   // truncate-pack 2 f32 -> u32
            pk.u[p] = (c[2 * p + 1].u & 0xFFFF0000u) | (c[2 * p].u >> 16);
        af[ks] = pk.s;
    }

    const short8* gw = reinterpret_cast<const short8*>(bfrag);

    f32x4 acc[8];
    #pragma unroll
    for (int ct = 0; ct < 8; ++ct) acc[ct] = (f32x4){0.f, 0.f, 0.f, 0.f};

    // SWAPPED operands: D = W^T_tile * emb^T_tile -> D[wcol][node]
    #pragma unroll
    for (int ct = 0; ct < 8; ++ct) {
        #pragma unroll
        for (int ks = 0; ks < 4; ++ks) {
            short8 wf = gw[(ks * 8 + ct) * 64 + lane];
            acc[ct] = __builtin_amdgcn_mfma_f32_16x16x32_bf16(wf, af[ks], acc[ct], 0, 0, 0);
        }
    }

    #pragma unroll
    for (int ct = 0; ct < 8; ++ct) {
        unsigned w = f2e5u(acc[ct][0])
                   | (f2e5u(acc[ct][1]) << 8)
                   | (f2e5u(acc[ct][2]) << 16)
                   | (f2e5u(acc[ct][3]) << 24);
        *reinterpret_cast<unsigned*>(&st[wave][(lane & 15) * 144 + ct * 16 + kg * 4]) = w;
    }
    // same-wave LDS RAW -> compiler inserts lgkmcnt wait; no barrier needed
    #pragma unroll
    for (int h = 0; h < 2; ++h) {
        int c   = lane + h * 64;
        int r   = c >> 3;                              // 0..15
        int off = (c & 7) * 16;                        // 0..112
        uint4 v = *reinterpret_cast<const uint4*>(&st[wave][r * 144 + off]);
        int node = ntile * 16 + r;
        if (node < N)
            *reinterpret_cast<uint4*>(P + (size_t)node * 128 + off) = v;
    }
}

// 16-unit partial MLP (lane covers units 16r..16r+15); no bias here.
__device__ inline float mlp16(uint4 A, uint4 B,
                              const unsigned* cnv, const unsigned* w2v)
{
    float sw = 0.f;
    unsigned aw[4] = {A.x, A.y, A.z, A.w};
    unsigned bw[4] = {B.x, B.y, B.z, B.w};
    #pragma unroll
    for (int w = 0; w < 4; ++w) {
        U32H2 a0, a1, b0, b1, c0, c1, W0, W1v;
        a0.u = (aw[w] << 8) & 0xFF00FF00u;
        a1.u =  aw[w]       & 0xFF00FF00u;
        b0.u = (bw[w] << 8) & 0xFF00FF00u;
        b1.u =  bw[w]       & 0xFF00FF00u;
        c0.u = cnv[2 * w];  c1.u = cnv[2 * w + 1];
        W0.u = w2v[2 * w];  W1v.u = w2v[2 * w + 1];
        h2 h0 = relu2(a0.h + b0.h + c0.h);
        h2 h1 = relu2(a1.h + b1.h + c1.h);
        sw = dot2acc(h0, W0.h, sw);
        sw = dot2acc(h1, W1v.h, sw);
    }
    return sw;
}

__device__ inline float gumbel_sigmoid(float uu, float sw) {
    float a = 0.9999f - 0.9998f * uu;                  // eps
    float b = 0.0001f + 0.9998f * uu;                  // 1-eps
    float gate = __logf(__fdividef(a, b));
    float x = (gate + sw) * 0.2f;                      // / TEMP
    return __fdividef(1.f, 1.f + __expf(-x));
}

// --- per-edge: quad (4 lanes) per edge, 2 edges per quad ---
__global__ __launch_bounds__(256) void pg_edge(
    const unsigned char* __restrict__ P,
    const unsigned* __restrict__ cnodeh, const unsigned* __restrict__ w2h,
    const float* __restrict__ b2, const float* __restrict__ u,
    const int* __restrict__ src, const int* __restrict__ dst,
    float* __restrict__ out, int E)
{
    int r    = threadIdx.x & 3;                        // lane-in-quad
    int quad = (blockIdx.x * 256 + threadIdx.x) >> 2;  // global quad
    int e0   = quad * 2;
    if (e0 >= E) return;
    bool two = (e0 + 1 < E);

    // hoist per-lane constant table slices (units 16r..16r+15)
    unsigned cnv[8], w2v[8];
    #pragma unroll
    for (int w = 0; w < 4; ++w) {
        int wi = 4 * r + w;
        cnv[2 * w]     = cnodeh[2 * wi];
        cnv[2 * w + 1] = cnodeh[2 * wi + 1];
        w2v[2 * w]     = w2h[2 * wi];
        w2v[2 * w + 1] = w2h[2 * wi + 1];
    }

    int2 sv, dv;
    if (two) {
        sv = *reinterpret_cast<const int2*>(src + e0);   // uniform in quad
        dv = *reinterpret_cast<const int2*>(dst + e0);
    } else {
        sv.x = sv.y = src[e0];
        dv.x = dv.y = dst[e0];
    }

    // quad-cooperative row loads: lanes r=0..3 -> consecutive 16B chunks
    uint4 A0 = *reinterpret_cast<const uint4*>(P + (size_t)sv.x * 128 + r * 16);
    uint4 B0 = *reinterpret_cast<const uint4*>(P + (size_t)dv.x * 128 + 64 + r * 16);
    uint4 A1 = *reinterpret_cast<const uint4*>(P + (size_t)sv.y * 128 + r * 16);
    uint4 B1 = *reinterpret_cast<const uint4*>(P + (size_t)dv.y * 128 + 64 + r * 16);

    float sw0 = mlp16(A0, B0, cnv, w2v);
    float sw1 = mlp16(A1, B1, cnv, w2v);

    // quad reduce (masks 1,2 stay within the quad)
    sw0 += __shfl_xor(sw0, 1); sw0 += __shfl_xor(sw0, 2);
    sw1 += __shfl_xor(sw1, 1); sw1 += __shfl_xor(sw1, 2);

    if (r == 0) {
        float bb = b2[0];
        if (two) {
            float2 uv = *reinterpret_cast<const float2*>(u + e0);
            float2 o;
            o.x = gumbel_sigmoid(uv.x, sw0 + bb);
            o.y = gumbel_sigmoid(uv.y, sw1 + bb);
            *reinterpret_cast<float2*>(out + e0) = o;
        } else {
            out[e0] = gumbel_sigmoid(u[e0], sw0 + bb);
        }
    }
}

extern "C" void kernel_launch(void* const* d_in, const int* in_sizes, int n_in,
                              void* d_out, int out_size, void* d_ws, size_t ws_size,
                              hipStream_t stream) {
    const float* embeds = (const float*)d_in[0];
    const float* W1     = (const float*)d_in[1];
    const float* b1     = (const float*)d_in[2];
    const float* W2     = (const float*)d_in[3];
    const float* b2     = (const float*)d_in[4];
    const float* u      = (const float*)d_in[5];
    const int*   src    = (const int*)d_in[6];
    const int*   dst    = (const int*)d_in[7];
    const int*   nidx   = (const int*)d_in[8];

    int E = in_sizes[6];
    int N = in_sizes[0] / D;
    int NTILES = (N + 15) / 16;

    // ws: bfrag 16384 bf16 (32KB) | cnodeh 32 u32 | w2h 32 u32 | P [N][128] u8
    unsigned short* bfrag = (unsigned short*)d_ws;
    unsigned* cnodeh = (unsigned*)(bfrag + 16384);
    unsigned* w2h    = cnodeh + 32;
    unsigned char* P = (unsigned char*)(w2h + 32);

    pg_prep<<<65, 256, 0, stream>>>(embeds, W1, b1, W2, nidx, bfrag, cnodeh, w2h);
    pg_nodes<<<(NTILES + 3) / 4, 256, 0, stream>>>(embeds, bfrag, P, N, NTILES);

    // 4 lanes per edge, 2 edges per quad
    long threads = ((long)E + 1) / 2 * 4;
    int blocks = (int)((threads + 255) / 256);
    pg_edge<<<blocks, 256, 0, stream>>>(P, cnodeh, w2h, b2, u,
                                        src, dst, (float*)d_out, E);
}